// Round 3
// baseline (193.856 us; speedup 1.0000x reference)
//
#include <hip/hip_runtime.h>

#define N_TOK 16384
#define DIM   1024
#define PATHS 8
#define CAP   4096
#define TPB   256
#define NBLK  (N_TOK / TPB)   // 64 routing blocks
#define RPB   8               // rows per gather block

// ---- workspace layout (bytes) ----
#define OFF_COUNTS 0          //  8 ints  (pad to 256)
#define OFF_BCNT   256        //  64*8 ints = 2048
#define OFF_PATH   2304       //  16384 ints = 65536
#define OFF_GATE   67840      //  16384 floats = 65536
#define OFF_INV    133376     //  8*4096 ints = 131072
#define OFF_GVAL   264448     //  8*4096 floats = 131072

// A1: per-token argmax/max + per-block path histogram
__global__ void k_route(const float* __restrict__ scores,
                        int* __restrict__ path, float* __restrict__ gate,
                        int* __restrict__ blockCnt) {
    __shared__ int cnt[PATHS];
    int tid = threadIdx.x;
    if (tid < PATHS) cnt[tid] = 0;
    __syncthreads();
    int t = blockIdx.x * TPB + tid;
    const float4* s4 = (const float4*)scores;
    float4 s0 = s4[t * 2];
    float4 s1 = s4[t * 2 + 1];
    float best = s0.x; int bp = 0;
    if (s0.y > best) { best = s0.y; bp = 1; }
    if (s0.z > best) { best = s0.z; bp = 2; }
    if (s0.w > best) { best = s0.w; bp = 3; }
    if (s1.x > best) { best = s1.x; bp = 4; }
    if (s1.y > best) { best = s1.y; bp = 5; }
    if (s1.z > best) { best = s1.z; bp = 6; }
    if (s1.w > best) { best = s1.w; bp = 7; }
    path[t] = bp;
    gate[t] = best;
    atomicAdd(&cnt[bp], 1);
    __syncthreads();
    if (tid < PATHS) blockCnt[blockIdx.x * PATHS + tid] = cnt[tid];
}

// A2: slot assignment; each block redundantly scans the 64x8 histogram (L2-hot).
__global__ void k_slot(const int* __restrict__ path, const float* __restrict__ gate,
                       const int* __restrict__ blockCnt,
                       int* __restrict__ counts,
                       int* __restrict__ inv, float* __restrict__ gval) {
    __shared__ int sBase[PATHS];
    __shared__ int wcnt[4 * PATHS];
    __shared__ int woff[4 * PATHS];
    int tid = threadIdx.x;
    if (tid < PATHS) {
        int p = tid;
        int run = 0, mine = 0;
        #pragma unroll
        for (int b = 0; b < NBLK; ++b) {
            if (b == (int)blockIdx.x) mine = run;
            run += blockCnt[b * PATHS + p];
        }
        sBase[p] = mine;
        if (blockIdx.x == 0) counts[p] = run;
    }
    int t = blockIdx.x * TPB + tid;
    int p = path[t];
    int lane = tid & 63;
    int wv = tid >> 6;
    unsigned long long lt_mask = (1ULL << lane) - 1ULL;
    int rank = 0;
    #pragma unroll
    for (int q = 0; q < PATHS; ++q) {
        unsigned long long m = __ballot(p == q);
        if (p == q) rank = __popcll(m & lt_mask);
        if (lane == 0) wcnt[wv * PATHS + q] = __popcll(m);
    }
    __syncthreads();
    if (tid < PATHS) {
        int run = 0;
        for (int w = 0; w < 4; ++w) {
            woff[w * PATHS + tid] = run;
            run += wcnt[w * PATHS + tid];
        }
    }
    __syncthreads();
    int slot = sBase[p] + woff[wv * PATHS + p] + rank;
    if (slot < CAP) {
        inv[p * CAP + slot] = t;
        gval[p * CAP + slot] = gate[t];
    }
}

// B: dense gather, RPB rows per block. All RPB row-loads issued before stores
// (independent global_load_dwordx4 in flight -> latency hidden by ILP, not
// just occupancy). inv/gval/counts indices are block-uniform -> scalar loads.
__global__ void __launch_bounds__(TPB) k_gather(
        const float4* __restrict__ x4,
        const int* __restrict__ inv, const float* __restrict__ gval,
        const int* __restrict__ counts,
        float4* __restrict__ out4) {
    int base = blockIdx.x * RPB;
    int tid = threadIdx.x;
    float4 v[RPB];
    #pragma unroll
    for (int r = 0; r < RPB; ++r) {
        int row = base + r;
        int p = row >> 12;             // CAP = 4096
        int s = row & (CAP - 1);
        if (s < counts[p]) {
            int t = inv[row];
            float g = gval[row];
            float4 u = x4[(size_t)t * (DIM / 4) + tid];
            v[r] = make_float4(u.x * g, u.y * g, u.z * g, u.w * g);
        } else {
            v[r] = make_float4(0.f, 0.f, 0.f, 0.f);
        }
    }
    #pragma unroll
    for (int r = 0; r < RPB; ++r) {
        out4[(size_t)(base + r) * (DIM / 4) + tid] = v[r];
    }
}

extern "C" void kernel_launch(void* const* d_in, const int* in_sizes, int n_in,
                              void* d_out, int out_size, void* d_ws, size_t ws_size,
                              hipStream_t stream) {
    const float* x      = (const float*)d_in[0];
    const float* scores = (const float*)d_in[1];
    float* out = (float*)d_out;
    char* ws = (char*)d_ws;

    int*   counts   = (int*)  (ws + OFF_COUNTS);
    int*   blockCnt = (int*)  (ws + OFF_BCNT);
    int*   path     = (int*)  (ws + OFF_PATH);
    float* gate     = (float*)(ws + OFF_GATE);
    int*   inv      = (int*)  (ws + OFF_INV);
    float* gval     = (float*)(ws + OFF_GVAL);

    k_route<<<NBLK, TPB, 0, stream>>>(scores, path, gate, blockCnt);
    k_slot<<<NBLK, TPB, 0, stream>>>(path, gate, blockCnt, counts, inv, gval);
    k_gather<<<(PATHS * CAP) / RPB, TPB, 0, stream>>>(
        (const float4*)x, inv, gval, counts, (float4*)out);
}

// Round 4
// 193.655 us; speedup vs baseline: 1.0010x; 1.0010x over previous
//
#include <hip/hip_runtime.h>

#define N_TOK 16384
#define DIM   1024
#define PATHS 8
#define CAP   4096
#define TPB   256
#define NBLK  (N_TOK / TPB)   // 64 routing blocks (all co-resident on 256 CUs)

// ---- workspace layout (bytes) ----
#define OFF_COUNTS 0          //  8 ints
#define OFF_CTR    128        //  1 int (arrival counter, memset to 0 each launch)
#define OFF_BCNT   256        //  64*8 ints = 2048
#define OFF_INV    2304       //  8*4096 ints = 131072
#define OFF_GVAL   133376     //  8*4096 floats = 131072

// Fused routing: per-token argmax/gate -> wave ballot ranks -> per-block
// histogram published with release atomics -> 64-block arrival barrier
// (device scope; all blocks co-resident) -> exclusive base scan -> slot
// assignment. path/gate never touch global memory.
__global__ void __launch_bounds__(TPB) k_route_slot(
        const float* __restrict__ scores,
        int* __restrict__ blockCnt, int* __restrict__ counter,
        int* __restrict__ counts,
        int* __restrict__ inv, float* __restrict__ gval) {
    __shared__ int wcnt[4 * PATHS];
    __shared__ int woff[4 * PATHS];
    __shared__ int sBase[PATHS];
    int tid = threadIdx.x;
    int t = blockIdx.x * TPB + tid;

    // --- route ---
    const float4* s4 = (const float4*)scores;
    float4 s0 = s4[t * 2];
    float4 s1 = s4[t * 2 + 1];
    float best = s0.x; int bp = 0;
    if (s0.y > best) { best = s0.y; bp = 1; }
    if (s0.z > best) { best = s0.z; bp = 2; }
    if (s0.w > best) { best = s0.w; bp = 3; }
    if (s1.x > best) { best = s1.x; bp = 4; }
    if (s1.y > best) { best = s1.y; bp = 5; }
    if (s1.z > best) { best = s1.z; bp = 6; }
    if (s1.w > best) { best = s1.w; bp = 7; }

    // --- per-wave ranks (token order preserved: lane order == token order) ---
    int lane = tid & 63;
    int wv = tid >> 6;
    unsigned long long lt_mask = (1ULL << lane) - 1ULL;
    int rank = 0;
    #pragma unroll
    for (int q = 0; q < PATHS; ++q) {
        unsigned long long m = __ballot(bp == q);
        if (bp == q) rank = __popcll(m & lt_mask);
        if (lane == 0) wcnt[wv * PATHS + q] = __popcll(m);
    }
    __syncthreads();

    // --- block histogram -> publish (release, agent scope) ---
    if (tid < PATHS) {
        int run = 0;
        #pragma unroll
        for (int w = 0; w < 4; ++w) {
            woff[w * PATHS + tid] = run;
            run += wcnt[w * PATHS + tid];
        }
        __hip_atomic_store(&blockCnt[blockIdx.x * PATHS + tid], run,
                           __ATOMIC_RELEASE, __HIP_MEMORY_SCOPE_AGENT);
    }
    __syncthreads();

    // --- 64-block arrival barrier (device-scope; blocks all co-resident) ---
    if (tid == 0) {
        __hip_atomic_fetch_add(counter, 1, __ATOMIC_ACQ_REL,
                               __HIP_MEMORY_SCOPE_AGENT);
        while (__hip_atomic_load(counter, __ATOMIC_ACQUIRE,
                                 __HIP_MEMORY_SCOPE_AGENT) < NBLK) { }
    }
    __syncthreads();

    // --- exclusive scan over block histograms (atomic loads bypass stale L1/L2) ---
    if (tid < PATHS) {
        int run = 0, mine = 0;
        #pragma unroll
        for (int b = 0; b < NBLK; ++b) {
            if (b == (int)blockIdx.x) mine = run;
            run += __hip_atomic_load(&blockCnt[b * PATHS + tid],
                                     __ATOMIC_RELAXED, __HIP_MEMORY_SCOPE_AGENT);
        }
        sBase[tid] = mine;
        if (blockIdx.x == 0) counts[tid] = run;   // consumed by next dispatch
    }
    __syncthreads();

    int slot = sBase[bp] + woff[wv * PATHS + bp] + rank;
    if (slot < CAP) {
        inv[bp * CAP + slot] = t;
        gval[bp * CAP + slot] = best;
    }
}

// B: dense gather (R2 form — measured best). One block per output row (p,s).
__global__ void k_gather(const float* __restrict__ x,
                         const int* __restrict__ inv, const float* __restrict__ gval,
                         const int* __restrict__ counts,
                         float* __restrict__ out) {
    int row = blockIdx.x;              // 0 .. PATHS*CAP-1
    int p = row >> 12;                 // CAP = 4096
    int s = row & (CAP - 1);
    int tid = threadIdx.x;
    float4* orow = (float4*)(out + (size_t)row * DIM);
    if (s < counts[p]) {
        int t = inv[row];
        float g = gval[row];
        const float4* xrow = (const float4*)(x + (size_t)t * DIM);
        float4 v = xrow[tid];
        v.x *= g; v.y *= g; v.z *= g; v.w *= g;
        orow[tid] = v;
    } else {
        orow[tid] = make_float4(0.f, 0.f, 0.f, 0.f);
    }
}

extern "C" void kernel_launch(void* const* d_in, const int* in_sizes, int n_in,
                              void* d_out, int out_size, void* d_ws, size_t ws_size,
                              hipStream_t stream) {
    const float* x      = (const float*)d_in[0];
    const float* scores = (const float*)d_in[1];
    float* out = (float*)d_out;
    char* ws = (char*)d_ws;

    int*   counts   = (int*)  (ws + OFF_COUNTS);
    int*   counter  = (int*)  (ws + OFF_CTR);
    int*   blockCnt = (int*)  (ws + OFF_BCNT);
    int*   inv      = (int*)  (ws + OFF_INV);
    float* gval     = (float*)(ws + OFF_GVAL);

    hipMemsetAsync(counter, 0, sizeof(int), stream);   // ws is poisoned each launch
    k_route_slot<<<NBLK, TPB, 0, stream>>>(scores, blockCnt, counter,
                                           counts, inv, gval);
    k_gather<<<PATHS * CAP, TPB, 0, stream>>>(x, inv, gval, counts, out);
}

// Round 5
// 190.140 us; speedup vs baseline: 1.0195x; 1.0185x over previous
//
#include <hip/hip_runtime.h>

#define N_TOK 16384
#define DIM   1024
#define PATHS 8
#define CAP   4096
#define TPB   256
#define NBLK  (N_TOK / TPB)   // 64 routing blocks

// ---- workspace layout (bytes) ----
#define OFF_COUNTS 0          //  8 ints  (pad to 256)
#define OFF_BCNT   256        //  64*8 ints = 2048
#define OFF_PATH   2304       //  16384 ints = 65536
#define OFF_GATE   67840      //  16384 floats = 65536
#define OFF_INV    133376     //  8*4096 ints = 131072
#define OFF_GVAL   264448     //  8*4096 floats = 131072

// A1: per-token argmax/max + per-block path histogram
__global__ void k_route(const float* __restrict__ scores,
                        int* __restrict__ path, float* __restrict__ gate,
                        int* __restrict__ blockCnt) {
    __shared__ int cnt[PATHS];
    int tid = threadIdx.x;
    if (tid < PATHS) cnt[tid] = 0;
    __syncthreads();
    int t = blockIdx.x * TPB + tid;
    const float4* s4 = (const float4*)scores;
    float4 s0 = s4[t * 2];
    float4 s1 = s4[t * 2 + 1];
    float best = s0.x; int bp = 0;
    if (s0.y > best) { best = s0.y; bp = 1; }
    if (s0.z > best) { best = s0.z; bp = 2; }
    if (s0.w > best) { best = s0.w; bp = 3; }
    if (s1.x > best) { best = s1.x; bp = 4; }
    if (s1.y > best) { best = s1.y; bp = 5; }
    if (s1.z > best) { best = s1.z; bp = 6; }
    if (s1.w > best) { best = s1.w; bp = 7; }
    path[t] = bp;
    gate[t] = best;
    atomicAdd(&cnt[bp], 1);
    __syncthreads();
    if (tid < PATHS) blockCnt[blockIdx.x * PATHS + tid] = cnt[tid];
}

// A2: slot assignment. Each block redundantly scans the tiny 64x8 histogram
// (2 KB, L2-resident) for its per-path exclusive base. Block 0 writes counts.
// Measured best structure (R2): no separate scan kernel, no spin barrier.
__global__ void k_slot(const int* __restrict__ path, const float* __restrict__ gate,
                       const int* __restrict__ blockCnt,
                       int* __restrict__ counts,
                       int* __restrict__ inv, float* __restrict__ gval) {
    __shared__ int sBase[PATHS];
    __shared__ int wcnt[4 * PATHS];
    __shared__ int woff[4 * PATHS];
    int tid = threadIdx.x;
    if (tid < PATHS) {
        int p = tid;
        int run = 0, mine = 0;
        #pragma unroll
        for (int b = 0; b < NBLK; ++b) {
            if (b == (int)blockIdx.x) mine = run;
            run += blockCnt[b * PATHS + p];
        }
        sBase[p] = mine;
        if (blockIdx.x == 0) counts[p] = run;
    }
    int t = blockIdx.x * TPB + tid;
    int p = path[t];
    int lane = tid & 63;
    int wv = tid >> 6;
    unsigned long long lt_mask = (1ULL << lane) - 1ULL;
    int rank = 0;
    #pragma unroll
    for (int q = 0; q < PATHS; ++q) {
        unsigned long long m = __ballot(p == q);
        if (p == q) rank = __popcll(m & lt_mask);
        if (lane == 0) wcnt[wv * PATHS + q] = __popcll(m);
    }
    __syncthreads();
    if (tid < PATHS) {
        int run = 0;
        for (int w = 0; w < 4; ++w) {
            woff[w * PATHS + tid] = run;
            run += wcnt[w * PATHS + tid];
        }
    }
    __syncthreads();
    int slot = sBase[p] + woff[wv * PATHS + p] + rank;
    if (slot < CAP) {
        inv[p * CAP + slot] = t;
        gval[p * CAP + slot] = gate[t];
    }
}

// B: dense gather into output. One block per output row (p, s); 256 threads
// x float4 = 1024 floats. Measured best gather (RPB=1; R3's RPB=8 regressed).
__global__ void k_gather(const float* __restrict__ x,
                         const int* __restrict__ inv, const float* __restrict__ gval,
                         const int* __restrict__ counts,
                         float* __restrict__ out) {
    int row = blockIdx.x;              // 0 .. PATHS*CAP-1
    int p = row >> 12;                 // CAP = 4096
    int s = row & (CAP - 1);
    int tid = threadIdx.x;
    float4* orow = (float4*)(out + (size_t)row * DIM);
    if (s < counts[p]) {
        int t = inv[row];
        float g = gval[row];
        const float4* xrow = (const float4*)(x + (size_t)t * DIM);
        float4 v = xrow[tid];
        v.x *= g; v.y *= g; v.z *= g; v.w *= g;
        orow[tid] = v;
    } else {
        orow[tid] = make_float4(0.f, 0.f, 0.f, 0.f);
    }
}

extern "C" void kernel_launch(void* const* d_in, const int* in_sizes, int n_in,
                              void* d_out, int out_size, void* d_ws, size_t ws_size,
                              hipStream_t stream) {
    const float* x      = (const float*)d_in[0];
    const float* scores = (const float*)d_in[1];
    float* out = (float*)d_out;
    char* ws = (char*)d_ws;

    int*   counts   = (int*)  (ws + OFF_COUNTS);
    int*   blockCnt = (int*)  (ws + OFF_BCNT);
    int*   path     = (int*)  (ws + OFF_PATH);
    float* gate     = (float*)(ws + OFF_GATE);
    int*   inv      = (int*)  (ws + OFF_INV);
    float* gval     = (float*)(ws + OFF_GVAL);

    k_route<<<NBLK, TPB, 0, stream>>>(scores, path, gate, blockCnt);
    k_slot<<<NBLK, TPB, 0, stream>>>(path, gate, blockCnt, counts, inv, gval);
    k_gather<<<PATHS * CAP, TPB, 0, stream>>>(x, inv, gval, counts, out);
}